// Round 1
// baseline (42716.544 us; speedup 1.0000x reference)
//
#include <hip/hip_runtime.h>
#include <hip/hip_bf16.h>
#include <hip/hip_cooperative_groups.h>
#include <cstddef>
#include <cstdint>

namespace cg = cooperative_groups;

#define DEVINL __device__ __forceinline__

constexpr int Bn = 128;   // batch
constexpr int Tn = 512;   // time
constexpr int Fn = 512;   // features
constexpr int Un = 256;   // units
constexpr int Gn = 1024;  // 4*U
constexpr int RS = 5;     // ring slots (5 so slot(t) != slot(t-1..t-4))

DEVINL float bf2f(__hip_bfloat16 v) { return __bfloat162float(v); }
DEVINL float ftanh(float x) { float e = __expf(2.f * x); return 1.f - 2.f / (e + 1.f); }
DEVINL float hsig(float x)  { return fminf(fmaxf(fmaf(x, 0.2f, 0.5f), 0.f), 1.f); }

DEVINL size_t RING(int d, int s, int b, int u) {
    return (((size_t)d * RS + s) * Bn + b) * (size_t)Un + u;
}
DEVINL size_t NIDX(int p, int d, int k, int s, int b) {
    return ((((size_t)p * 2 + d) * 2 + k) * RS + s) * Bn + b;
}

DEVINL void softmax4(float* s) {
    float mx = fmaxf(fmaxf(s[0], s[1]), fmaxf(s[2], s[3]));
    float e0 = __expf(s[0] - mx), e1 = __expf(s[1] - mx);
    float e2 = __expf(s[2] - mx), e3 = __expf(s[3] - mx);
    float inv = 1.f / (e0 + e1 + e2 + e3);
    s[0] = e0 * inv; s[1] = e1 * inv; s[2] = e2 * inv; s[3] = e3 * inv;
}

// ---------------------------------------------------------------------------
// Phase 1: C[m,n] = sum_k A[m,k] * W[k,n]; A is (B*T, F) row-major (m = b*T+t)
// Output written bf16 at out[(t*B+b)*N + n]  (time-major, per-step contiguous)
// ---------------------------------------------------------------------------
__global__ __launch_bounds__(256)
void gemm_x(const float* __restrict__ A, const float* __restrict__ W, int N,
            __hip_bfloat16* __restrict__ out)
{
    __shared__ __align__(16) float As[16][68];  // [k][m]
    __shared__ __align__(16) float Bs[16][68];  // [k][n]
    const int tid = threadIdx.x;
    const int n0 = blockIdx.x * 64;
    const int m0 = blockIdx.y * 64;
    const int tx = tid & 15, ty = tid >> 4;
    const int arow = tid >> 2, akq = (tid & 3) * 4;
    const int bk = tid >> 4, bn = (tid & 15) * 4;
    const float* aptr = A + (size_t)(m0 + arow) * Fn + akq;
    const float* bptr = W + (size_t)bk * N + n0 + bn;
    float acc[4][4] = {};
    for (int k0 = 0; k0 < Fn; k0 += 16) {
        float4 av = *(const float4*)(aptr + k0);
        float4 bv = *(const float4*)(bptr + (size_t)k0 * N);
        __syncthreads();
        As[akq + 0][arow] = av.x;
        As[akq + 1][arow] = av.y;
        As[akq + 2][arow] = av.z;
        As[akq + 3][arow] = av.w;
        *(float4*)&Bs[bk][bn] = bv;
        __syncthreads();
        #pragma unroll
        for (int kk = 0; kk < 16; kk++) {
            float4 a = *(const float4*)&As[kk][ty * 4];
            float4 b = *(const float4*)&Bs[kk][tx * 4];
            acc[0][0] += a.x * b.x; acc[0][1] += a.x * b.y; acc[0][2] += a.x * b.z; acc[0][3] += a.x * b.w;
            acc[1][0] += a.y * b.x; acc[1][1] += a.y * b.y; acc[1][2] += a.y * b.z; acc[1][3] += a.y * b.w;
            acc[2][0] += a.z * b.x; acc[2][1] += a.z * b.y; acc[2][2] += a.z * b.z; acc[2][3] += a.z * b.w;
            acc[3][0] += a.w * b.x; acc[3][1] += a.w * b.y; acc[3][2] += a.w * b.z; acc[3][3] += a.w * b.w;
        }
    }
    #pragma unroll
    for (int i = 0; i < 4; i++) {
        int m = m0 + ty * 4 + i;
        int b = m >> 9, t = m & (Tn - 1);
        __hip_bfloat16* op = out + ((size_t)t * Bn + b) * N + n0 + tx * 4;
        #pragma unroll
        for (int j = 0; j < 4; j++) op[j] = __float2bfloat16(acc[i][j]);
    }
}

// ---------------------------------------------------------------------------
// Elementwise score-norm: norms[par][d][kind][slot][b] = sum_u tanh(proj+xW)^2
// for 8 rows starting at r0 (full 256-col rows per block).
// ---------------------------------------------------------------------------
DEVINL void ew_norms(const float* __restrict__ proj, const __hip_bfloat16* __restrict__ xW,
                     int d, int slot, int kind, int r0, int tt, int par,
                     float* __restrict__ norms, int tid, float* red)
{
    float ssq[8];
    #pragma unroll
    for (int ii = 0; ii < 8; ii++) {
        int b = r0 + ii;
        float p  = proj[RING(d, slot, b, tid)];
        float xv = bf2f(xW[((size_t)tt * Bn + b) * Un + tid]);
        float a  = ftanh(p + xv);
        ssq[ii] = a * a;
    }
    #pragma unroll
    for (int ii = 0; ii < 8; ii++) {
        float v = ssq[ii];
        #pragma unroll
        for (int m = 32; m; m >>= 1) v += __shfl_xor(v, m, 64);
        if ((tid & 63) == 0) red[(tid >> 6) * 8 + ii] = v;
    }
    __syncthreads();
    if (tid < 8) {
        float s = red[tid] + red[8 + tid] + red[16 + tid] + red[24 + tid];
        norms[NIDX(par, d, kind, slot, r0 + tid)] = s;
    }
    __syncthreads();
}

// ---------------------------------------------------------------------------
// Phase 2: the whole bidirectional scan in one cooperative kernel.
// 256 blocks x 256 threads; 2 grid.sync per step.
// ---------------------------------------------------------------------------
__global__ __launch_bounds__(256)
void recurrence(const __hip_bfloat16* __restrict__ xg,
                const __hip_bfloat16* __restrict__ xWh,
                const __hip_bfloat16* __restrict__ xWc,
                const float* __restrict__ rk,
                const float* __restrict__ Whm,   // attention_h base: rows 0..255 = state part
                const float* __restrict__ Wcm,   // attention_c base
                float* __restrict__ Hring, float* __restrict__ Cring,
                float* __restrict__ PH, float* __restrict__ PCc, float* __restrict__ PCh,
                float* __restrict__ norms,
                float* __restrict__ hsF, float* __restrict__ hsB)
{
    cg::grid_group grid = cg::this_grid();
    const int tid = threadIdx.x;
    const int bid = blockIdx.x;

    __shared__ __align__(16) float hm[8][256];      // hmix rows / stage-C A-tile
    __shared__ __align__(16) float gbuf[8][4][32];  // g tile (r, gate, u)
    __shared__ float swh[4][8];
    __shared__ float swc[4][8];
    __shared__ float red[32];

    // ---- init: zero rings / proj caches / norms ----
    {
        const int gstride = 256 * 256;
        int gt = bid * 256 + tid;
        for (int i = gt; i < 2 * RS * Bn * Un; i += gstride) {
            Hring[i] = 0.f; Cring[i] = 0.f; PH[i] = 0.f; PCc[i] = 0.f; PCh[i] = 0.f;
        }
        for (int i = gt; i < 2 * 2 * 2 * RS * Bn; i += gstride) norms[i] = 0.f;
    }
    grid.sync();

    // ---- prepass: norms for step 0 (parity 0); all projections are zero ----
    {
        int d = bid >> 7, rem = bid & 127;
        int item = rem >> 4, r0 = (rem & 15) * 8;
        int kind = item >> 2, j = (item & 3) + 1;
        int slot = (0 - j + RS) % RS;
        int tt = d ? (Tn - 1) : 0;
        const float* proj = (kind == 0) ? PH : (j == 4 ? PCh : PCc);
        const __hip_bfloat16* xW = (kind == 0 || j == 4) ? xWh : xWc;
        ew_norms(proj, xW, d, slot, kind, r0, tt, 0, norms, tid, red);
    }
    grid.sync();

    for (int t = 0; t < Tn; t++) {
        const int par = t & 1, npar = par ^ 1;
        const int st = t % RS;
        int sj[4];
        #pragma unroll
        for (int j = 0; j < 4; j++) sj[j] = (t - 1 - j + 2 * RS) % RS;  // slot of h_{j+1}=h(t-1-j)

        // ================= STAGE B =================
        // 256 units: unit = bid; d, 16 row-tiles(8), 8 u-tiles(32)
        {
            const int d = bid >> 7, rem = bid & 127;
            const int r0 = (rem >> 3) * 8;
            const int u0 = (rem & 7) * 32;
            const int tt = d ? (Tn - 1 - t) : t;

            if (tid < 8) {
                int b = r0 + tid;
                float sh[4], sc[4];
                #pragma unroll
                for (int j = 0; j < 4; j++) {
                    sh[j] = sqrtf(norms[NIDX(par, d, 0, sj[j], b)]);
                    sc[j] = sqrtf(norms[NIDX(par, d, 1, sj[j], b)]);
                }
                softmax4(sh); softmax4(sc);
                #pragma unroll
                for (int j = 0; j < 4; j++) { swh[j][tid] = sh[j]; swc[j][tid] = sc[j]; }
            }
            // zero next-parity fused-norm accumulators for slot st (one u-block per row-tile)
            if ((rem & 7) == 0 && tid < 16) {
                norms[NIDX(npar, d, tid >> 3, st, r0 + (tid & 7))] = 0.f;
            }
            __syncthreads();

            // hmix rows (full 256 cols) into LDS
            #pragma unroll
            for (int ii = 0; ii < 8; ii++) {
                int b = r0 + ii;
                float acc = 0.f;
                #pragma unroll
                for (int j = 0; j < 4; j++) acc += swh[j][ii] * Hring[RING(d, sj[j], b, tid)];
                hm[ii][tid] = fmaxf(acc, 0.f);
            }
            // cmix only for this block's (r,u) epilogue element
            float cmreg;
            {
                int r = tid >> 5, uu = u0 + (tid & 31), b = r0 + r;
                float acc = 0.f;
                #pragma unroll
                for (int j = 0; j < 4; j++) acc += swc[j][r] * Cring[RING(d, sj[j], b, uu)];
                cmreg = fmaxf(acc, 0.f);
            }
            __syncthreads();

            // GEMM: g[r, q*256+u] = sum_k hm[r][k] * rk[k][q*256+u]
            {
                const int r = tid >> 5, q = (tid >> 3) & 3, ug = tid & 7;
                const int col0 = q * Un + u0 + ug * 4;
                float ax = 0, ay = 0, az = 0, aw = 0;
                const float* rbase = rk + col0;
                #pragma unroll 2
                for (int k0 = 0; k0 < Un; k0 += 4) {
                    float4 av = *(const float4*)&hm[r][k0];
                    const float* rp = rbase + (size_t)k0 * Gn;
                    float4 w0 = *(const float4*)(rp);
                    float4 w1 = *(const float4*)(rp + Gn);
                    float4 w2 = *(const float4*)(rp + 2 * Gn);
                    float4 w3 = *(const float4*)(rp + 3 * Gn);
                    ax += av.x * w0.x + av.y * w1.x + av.z * w2.x + av.w * w3.x;
                    ay += av.x * w0.y + av.y * w1.y + av.z * w2.y + av.w * w3.y;
                    az += av.x * w0.z + av.y * w1.z + av.z * w2.z + av.w * w3.z;
                    aw += av.x * w0.w + av.y * w1.w + av.z * w2.w + av.w * w3.w;
                }
                gbuf[r][q][ug * 4 + 0] = ax;
                gbuf[r][q][ug * 4 + 1] = ay;
                gbuf[r][q][ug * 4 + 2] = az;
                gbuf[r][q][ug * 4 + 3] = aw;
            }
            __syncthreads();

            // gates epilogue
            {
                const int r = tid >> 5, ui = tid & 31;
                const int b = r0 + r, uu = u0 + ui;
                const size_t xb = ((size_t)tt * Bn + b) * Gn + uu;
                float g0 = gbuf[r][0][ui] + bf2f(xg[xb]);
                float g1 = gbuf[r][1][ui] + bf2f(xg[xb + Un]);
                float g2 = gbuf[r][2][ui] + bf2f(xg[xb + 2 * Un]);
                float g3 = gbuf[r][3][ui] + bf2f(xg[xb + 3 * Un]);
                float gi = hsig(g0), gf = hsig(g1), gm = hsig(g2), go = hsig(g3);
                float c = gf * cmreg + gi * gm;
                float h = go * ftanh(c);
                Hring[RING(d, st, b, uu)] = h;
                Cring[RING(d, st, b, uu)] = c;
                float* hs = d ? hsB : hsF;
                hs[((size_t)tt * Bn + b) * Un + uu] = h;
            }
        }
        grid.sync();
        if (t == Tn - 1) break;

        // ================= STAGE C =================
        // 192 GEMM units (2d x 3mats x 16 rowtiles x 2 coltiles) + 192 ew units
        {
            const int tn = t + 1;
            for (int unit = bid; unit < 384; unit += 256) {
                if (unit < 192) {
                    const int d = unit / 96;
                    const int g2 = unit % 96;
                    const int mat = g2 >> 5;
                    const int rem = g2 & 31;
                    const int r0 = (rem >> 1) * 8, n0 = (rem & 1) * 128;
                    const int ttn = d ? (Tn - 1 - tn) : tn;
                    const float* state = (mat == 0) ? Hring : Cring;
                    const float* W = (mat == 1) ? Wcm : Whm;
                    float* proj = (mat == 0) ? PH : (mat == 1 ? PCc : PCh);
                    __syncthreads();  // protect hm reuse
                    #pragma unroll
                    for (int ii = 0; ii < 8; ii++)
                        hm[ii][tid] = state[RING(d, st, r0 + ii, tid)];
                    __syncthreads();
                    const int r = tid >> 5, ug = tid & 31;
                    const int n = n0 + ug * 4;
                    float ax = 0, ay = 0, az = 0, aw = 0;
                    const float* wbase = W + n;
                    #pragma unroll 2
                    for (int k0 = 0; k0 < Un; k0 += 4) {
                        float4 av = *(const float4*)&hm[r][k0];
                        const float* wp = wbase + (size_t)k0 * Un;
                        float4 w0 = *(const float4*)(wp);
                        float4 w1 = *(const float4*)(wp + Un);
                        float4 w2 = *(const float4*)(wp + 2 * Un);
                        float4 w3 = *(const float4*)(wp + 3 * Un);
                        ax += av.x * w0.x + av.y * w1.x + av.z * w2.x + av.w * w3.x;
                        ay += av.x * w0.y + av.y * w1.y + av.z * w2.y + av.w * w3.y;
                        az += av.x * w0.z + av.y * w1.z + av.z * w2.z + av.w * w3.z;
                        aw += av.x * w0.w + av.y * w1.w + av.z * w2.w + av.w * w3.w;
                    }
                    const int b = r0 + r;
                    float4 res; res.x = ax; res.y = ay; res.z = az; res.w = aw;
                    *(float4*)&proj[RING(d, st, b, n)] = res;
                    if (mat < 2) {
                        // fused next-step norm for the NEW state (j=1, slot st)
                        const __hip_bfloat16* xW = (mat == 0) ? xWh : xWc;
                        const size_t xb = ((size_t)ttn * Bn + b) * Un + n;
                        float a0 = ftanh(ax + bf2f(xW[xb + 0]));
                        float a1 = ftanh(ay + bf2f(xW[xb + 1]));
                        float a2v = ftanh(az + bf2f(xW[xb + 2]));
                        float a3 = ftanh(aw + bf2f(xW[xb + 3]));
                        float ss = a0 * a0 + a1 * a1 + a2v * a2v + a3 * a3;
                        #pragma unroll
                        for (int m = 16; m; m >>= 1) ss += __shfl_xor(ss, m, 32);
                        if (ug == 0) atomicAdd(&norms[NIDX(npar, d, mat, st, b)], ss);
                    }
                } else {
                    // elementwise norms for cached states j=2..4 (next step)
                    const int e = unit - 192;
                    const int d = e / 96;
                    const int e2 = e % 96;
                    const int item = e2 >> 4;
                    const int r0 = (e2 & 15) * 8;
                    const int kind = item / 3;
                    const int j = (item % 3) + 2;
                    const int slot = (tn - j + 2 * RS) % RS;
                    const int ttn = d ? (Tn - 1 - tn) : tn;
                    const float* proj = (kind == 0) ? PH : (j == 4 ? PCh : PCc);
                    const __hip_bfloat16* xW = (kind == 0 || j == 4) ? xWh : xWc;
                    __syncthreads();
                    ew_norms(proj, xW, d, slot, kind, r0, ttn, npar, norms, tid, red);
                }
            }
        }
        grid.sync();
    }
}

// ---------------------------------------------------------------------------
// Phase 3: ha = relu(outs@A11)@a2 ; hb = relu(x@A12)@a2_2 ; out = tanh(ha*outs+hb)
// One block per 8 (b,t) rows.
// ---------------------------------------------------------------------------
__global__ __launch_bounds__(256)
void final_k(const float* __restrict__ x, const float* __restrict__ hsF, const float* __restrict__ hsB,
             const float* __restrict__ at1, const float* __restrict__ at2, const float* __restrict__ at22,
             float* __restrict__ out)
{
    __shared__ __align__(16) float orow[8][512];
    __shared__ __align__(16) float xrow[8][512];
    __shared__ float has[8], hbs[8];
    const int tid = threadIdx.x;
    const int m0 = blockIdx.x * 8;
    for (int e = tid; e < 8 * 512; e += 256) {
        int r = e >> 9, k = e & 511;
        int m = m0 + r, b = m >> 9, t = m & 511;
        float ov = (k < 256) ? hsF[((size_t)t * Bn + b) * Un + k]
                             : hsB[((size_t)t * Bn + b) * Un + (k - 256)];
        orow[r][k] = ov;
        xrow[r][k] = x[((size_t)b * Tn + t) * Fn + k];
    }
    __syncthreads();
    const int r = tid >> 5, us = tid & 31;
    float ya[8] = {}, yb[8] = {};
    const float* pa0 = at1 + us * 8;
    const float* pb0 = at1 + (size_t)512 * 256 + us * 8;
    for (int k = 0; k < 512; k++) {
        float a  = orow[r][k];
        float xv = xrow[r][k];
        const float* pa = pa0 + (size_t)k * 256;
        const float* pb = pb0 + (size_t)k * 256;
        float4 wa0 = *(const float4*)pa;
        float4 wa1 = *(const float4*)(pa + 4);
        float4 wb0 = *(const float4*)pb;
        float4 wb1 = *(const float4*)(pb + 4);
        ya[0] += a * wa0.x; ya[1] += a * wa0.y; ya[2] += a * wa0.z; ya[3] += a * wa0.w;
        ya[4] += a * wa1.x; ya[5] += a * wa1.y; ya[6] += a * wa1.z; ya[7] += a * wa1.w;
        yb[0] += xv * wb0.x; yb[1] += xv * wb0.y; yb[2] += xv * wb0.z; yb[3] += xv * wb0.w;
        yb[4] += xv * wb1.x; yb[5] += xv * wb1.y; yb[6] += xv * wb1.z; yb[7] += xv * wb1.w;
    }
    float4 a20  = *(const float4*)(at2 + us * 8);
    float4 a21  = *(const float4*)(at2 + us * 8 + 4);
    float4 a220 = *(const float4*)(at22 + us * 8);
    float4 a221 = *(const float4*)(at22 + us * 8 + 4);
    float pa_s = fmaxf(ya[0], 0.f) * a20.x + fmaxf(ya[1], 0.f) * a20.y
               + fmaxf(ya[2], 0.f) * a20.z + fmaxf(ya[3], 0.f) * a20.w
               + fmaxf(ya[4], 0.f) * a21.x + fmaxf(ya[5], 0.f) * a21.y
               + fmaxf(ya[6], 0.f) * a21.z + fmaxf(ya[7], 0.f) * a21.w;
    float pb_s = fmaxf(yb[0], 0.f) * a220.x + fmaxf(yb[1], 0.f) * a220.y
               + fmaxf(yb[2], 0.f) * a220.z + fmaxf(yb[3], 0.f) * a220.w
               + fmaxf(yb[4], 0.f) * a221.x + fmaxf(yb[5], 0.f) * a221.y
               + fmaxf(yb[6], 0.f) * a221.z + fmaxf(yb[7], 0.f) * a221.w;
    #pragma unroll
    for (int m = 16; m; m >>= 1) {
        pa_s += __shfl_xor(pa_s, m, 32);
        pb_s += __shfl_xor(pb_s, m, 32);
    }
    if (us == 0) { has[r] = pa_s; hbs[r] = pb_s; }
    __syncthreads();
    for (int e = tid; e < 8 * 512; e += 256) {
        int rr = e >> 9, k = e & 511;
        float v = ftanh(has[rr] * orow[rr][k] + hbs[rr]);
        out[(size_t)(m0 + rr) * 512 + k] = v;
    }
}

// ---------------------------------------------------------------------------
extern "C" void kernel_launch(void* const* d_in, const int* in_sizes, int n_in,
                              void* d_out, int out_size, void* d_ws, size_t ws_size,
                              hipStream_t stream)
{
    (void)in_sizes; (void)n_in; (void)out_size; (void)ws_size;
    const float* x    = (const float*)d_in[0];
    const float* wk   = (const float*)d_in[1];  // kernel (F, 4U)
    const float* rk   = (const float*)d_in[2];  // recurrent_kernel (U, 4U)
    const float* ath  = (const float*)d_in[3];  // attention_h (F+U, U)
    const float* atc  = (const float*)d_in[4];  // attention_c (F+U, U)
    const float* at1  = (const float*)d_in[5];  // attention1 (2U+F, U)
    const float* at2  = (const float*)d_in[7];  // attention2 (U, 1)
    const float* at22 = (const float*)d_in[8];  // attention2_2 (U, 1)
    float* out = (float*)d_out;

    char* p = (char*)d_ws;
    auto take = [&](size_t bytes) { char* q = p; p += (bytes + 255) & ~(size_t)255; return q; };
    __hip_bfloat16* xg  = (__hip_bfloat16*)take((size_t)Tn * Bn * Gn * 2);  // 134 MB
    __hip_bfloat16* xWh = (__hip_bfloat16*)take((size_t)Tn * Bn * Un * 2);  //  33 MB
    __hip_bfloat16* xWc = (__hip_bfloat16*)take((size_t)Tn * Bn * Un * 2);
    float* hsF   = (float*)take((size_t)Tn * Bn * Un * 4);                  //  67 MB
    float* hsB   = (float*)take((size_t)Tn * Bn * Un * 4);
    float* Hring = (float*)take((size_t)2 * RS * Bn * Un * 4);
    float* Cring = (float*)take((size_t)2 * RS * Bn * Un * 4);
    float* PH    = (float*)take((size_t)2 * RS * Bn * Un * 4);
    float* PCc   = (float*)take((size_t)2 * RS * Bn * Un * 4);
    float* PCh   = (float*)take((size_t)2 * RS * Bn * Un * 4);
    float* norms = (float*)take((size_t)2 * 2 * 2 * RS * Bn * 4);

    // Phase 1: x-projections (time-parallel)
    gemm_x<<<dim3(Gn / 64, (Bn * Tn) / 64), 256, 0, stream>>>(x, wk, Gn, xg);
    gemm_x<<<dim3(Un / 64, (Bn * Tn) / 64), 256, 0, stream>>>(x, ath + (size_t)Un * Un, Un, xWh);
    gemm_x<<<dim3(Un / 64, (Bn * Tn) / 64), 256, 0, stream>>>(x, atc + (size_t)Un * Un, Un, xWc);

    // Phase 2: bidirectional scan (cooperative)
    void* args[] = { (void*)&xg, (void*)&xWh, (void*)&xWc, (void*)&rk, (void*)&ath, (void*)&atc,
                     (void*)&Hring, (void*)&Cring, (void*)&PH, (void*)&PCc, (void*)&PCh,
                     (void*)&norms, (void*)&hsF, (void*)&hsB };
    hipLaunchCooperativeKernel((void*)recurrence, dim3(256), dim3(256), args, 0, stream);

    // Phase 3: output attention + tanh
    final_k<<<dim3((Bn * Tn) / 8), 256, 0, stream>>>(x, hsF, hsB, at1, at2, at22, out);
}

// Round 2
// 9995.898 us; speedup vs baseline: 4.2734x; 4.2734x over previous
//
#include <hip/hip_runtime.h>
#include <hip/hip_bf16.h>
#include <cstddef>
#include <cstdint>

#define DEVINL __device__ __forceinline__

constexpr int Bn = 128;   // batch
constexpr int Tn = 512;   // time
constexpr int Fn = 512;   // features
constexpr int Un = 256;   // units
constexpr int Gn = 1024;  // 4*U
constexpr int RS = 5;     // ring slots

DEVINL float bf2f(__hip_bfloat16 v) { return __bfloat162float(v); }
DEVINL float ftanh(float x) { float e = __expf(2.f * x); return 1.f - 2.f / (e + 1.f); }
DEVINL float hsig(float x)  { return fminf(fmaxf(fmaf(x, 0.2f, 0.5f), 0.f), 1.f); }

DEVINL void softmax4(float* s) {
    float mx = fmaxf(fmaxf(s[0], s[1]), fmaxf(s[2], s[3]));
    float e0 = __expf(s[0] - mx), e1 = __expf(s[1] - mx);
    float e2 = __expf(s[2] - mx), e3 = __expf(s[3] - mx);
    float inv = 1.f / (e0 + e1 + e2 + e3);
    s[0] = e0 * inv; s[1] = e1 * inv; s[2] = e2 * inv; s[3] = e3 * inv;
}

// 8 bf16 packed in a uint4, paired with h[0..7] -> acc
DEVINL float dot8(uint4 w, float4 h0, float4 h1, float acc) {
    acc = fmaf(__uint_as_float(w.x << 16),          h0.x, acc);
    acc = fmaf(__uint_as_float(w.x & 0xffff0000u),  h0.y, acc);
    acc = fmaf(__uint_as_float(w.y << 16),          h0.z, acc);
    acc = fmaf(__uint_as_float(w.y & 0xffff0000u),  h0.w, acc);
    acc = fmaf(__uint_as_float(w.z << 16),          h1.x, acc);
    acc = fmaf(__uint_as_float(w.z & 0xffff0000u),  h1.y, acc);
    acc = fmaf(__uint_as_float(w.w << 16),          h1.z, acc);
    acc = fmaf(__uint_as_float(w.w & 0xffff0000u),  h1.w, acc);
    return acc;
}

// ---------------------------------------------------------------------------
// Phase 1: C[m,n] = sum_k A[m,k] * W[k,n]; A is (B*T, F) row-major (m = b*T+t)
// Output written bf16 at out[(t*B+b)*N + n]  (time-major, per-step contiguous)
// ---------------------------------------------------------------------------
__global__ __launch_bounds__(256)
void gemm_x(const float* __restrict__ A, const float* __restrict__ W, int N,
            __hip_bfloat16* __restrict__ out)
{
    __shared__ __align__(16) float As[16][68];  // [k][m]
    __shared__ __align__(16) float Bs[16][68];  // [k][n]
    const int tid = threadIdx.x;
    const int n0 = blockIdx.x * 64;
    const int m0 = blockIdx.y * 64;
    const int tx = tid & 15, ty = tid >> 4;
    const int arow = tid >> 2, akq = (tid & 3) * 4;
    const int bk = tid >> 4, bn = (tid & 15) * 4;
    const float* aptr = A + (size_t)(m0 + arow) * Fn + akq;
    const float* bptr = W + (size_t)bk * N + n0 + bn;
    float acc[4][4] = {};
    for (int k0 = 0; k0 < Fn; k0 += 16) {
        float4 av = *(const float4*)(aptr + k0);
        float4 bv = *(const float4*)(bptr + (size_t)k0 * N);
        __syncthreads();
        As[akq + 0][arow] = av.x;
        As[akq + 1][arow] = av.y;
        As[akq + 2][arow] = av.z;
        As[akq + 3][arow] = av.w;
        *(float4*)&Bs[bk][bn] = bv;
        __syncthreads();
        #pragma unroll
        for (int kk = 0; kk < 16; kk++) {
            float4 a = *(const float4*)&As[kk][ty * 4];
            float4 b = *(const float4*)&Bs[kk][tx * 4];
            acc[0][0] += a.x * b.x; acc[0][1] += a.x * b.y; acc[0][2] += a.x * b.z; acc[0][3] += a.x * b.w;
            acc[1][0] += a.y * b.x; acc[1][1] += a.y * b.y; acc[1][2] += a.y * b.z; acc[1][3] += a.y * b.w;
            acc[2][0] += a.z * b.x; acc[2][1] += a.z * b.y; acc[2][2] += a.z * b.z; acc[2][3] += a.z * b.w;
            acc[3][0] += a.w * b.x; acc[3][1] += a.w * b.y; acc[3][2] += a.w * b.z; acc[3][3] += a.w * b.w;
        }
    }
    #pragma unroll
    for (int i = 0; i < 4; i++) {
        int m = m0 + ty * 4 + i;
        int b = m >> 9, t = m & (Tn - 1);
        __hip_bfloat16* op = out + ((size_t)t * Bn + b) * N + n0 + tx * 4;
        #pragma unroll
        for (int j = 0; j < 4; j++) op[j] = __float2bfloat16(acc[i][j]);
    }
}

// ---------------------------------------------------------------------------
// Phase 0b: pack weights to bf16 in k-interleaved layout.
// rkP[(kc*1024+n)*8+i]  = rk[kc*8+i][n]      (kc<32, n<1024)
// WhP[(kc*256+n)*8+i]   = ath[kc*8+i][n]     (state half, rows 0..255)
// WcP[(kc*256+n)*8+i]   = atc[kc*8+i][n]
// ---------------------------------------------------------------------------
__global__ __launch_bounds__(256)
void pack_w(const float* __restrict__ rk, const float* __restrict__ ath,
            const float* __restrict__ atc,
            __hip_bfloat16* __restrict__ rkP, __hip_bfloat16* __restrict__ WhP,
            __hip_bfloat16* __restrict__ WcP)
{
    int idx = blockIdx.x * 256 + threadIdx.x;
    const int stride = gridDim.x * 256;
    for (int e = idx; e < 32 * 1024 * 8; e += stride) {
        int i = e & 7, n = (e >> 3) & 1023, kc = e >> 13;
        rkP[e] = __float2bfloat16(rk[(size_t)(kc * 8 + i) * Gn + n]);
    }
    for (int e = idx; e < 32 * 256 * 8; e += stride) {
        int i = e & 7, n = (e >> 3) & 255, kc = e >> 11;
        WhP[e] = __float2bfloat16(ath[(size_t)(kc * 8 + i) * Un + n]);
        WcP[e] = __float2bfloat16(atc[(size_t)(kc * 8 + i) * Un + n]);
    }
}

// ---------------------------------------------------------------------------
// Phase 2: batch-parallel recurrence. One WG per (direction, batch row).
// All recurrent state in LDS; zero grid syncs.
// ---------------------------------------------------------------------------
__global__ __launch_bounds__(256)
void recurrence(const __hip_bfloat16* __restrict__ xg,
                const __hip_bfloat16* __restrict__ xWh,
                const __hip_bfloat16* __restrict__ xWc,
                const __hip_bfloat16* __restrict__ rkP,
                const __hip_bfloat16* __restrict__ WhP,
                const __hip_bfloat16* __restrict__ WcP,
                float* __restrict__ hsF, float* __restrict__ hsB)
{
    const int tid = threadIdx.x;
    const int d = blockIdx.x >> 7;         // 0 = fwd, 1 = bwd
    const int b = blockIdx.x & 127;

    __shared__ __align__(16) float Hr[RS][Un];
    __shared__ __align__(16) float Cr[RS][Un];
    __shared__ __align__(16) float PHr[RS][Un];   // h_j @ Wh  cache
    __shared__ __align__(16) float PCcr[RS][Un];  // c_j @ Wc  cache
    __shared__ __align__(16) float PChr[RS][Un];  // c_j @ Wh  cache (j=4 score)
    __shared__ __align__(16) float hm[Un];
    __shared__ __align__(16) float cm[Un];
    __shared__ float red[32];
    __shared__ float sc8[8];
    __shared__ float wsm[8];

    // zero rings
    #pragma unroll
    for (int s = 0; s < RS; s++) {
        Hr[s][tid] = 0.f; Cr[s][tid] = 0.f;
        PHr[s][tid] = 0.f; PCcr[s][tid] = 0.f; PChr[s][tid] = 0.f;
    }
    __syncthreads();

    float* hs = d ? hsB : hsF;
    const int lane = tid & 63, wid = tid >> 6;

    for (int t = 0; t < Tn; t++) {
        const int tt = d ? (Tn - 1 - t) : t;
        const int st = t % RS;
        int sj[4];
        #pragma unroll
        for (int j = 0; j < 4; j++) sj[j] = (t - 1 - j + 2 * RS) % RS;

        const size_t rowx = ((size_t)tt * Bn + b);

        // prefetch xg for this step (used in gate epilogue)
        const __hip_bfloat16* xgp = xg + rowx * Gn + tid;
        __hip_bfloat16 xg0 = xgp[0], xg1 = xgp[Un], xg2 = xgp[2 * Un], xg3 = xgp[3 * Un];

        // ---- scores ----
        float xh = bf2f(xWh[rowx * Un + tid]);
        float xc = bf2f(xWc[rowx * Un + tid]);
        float vals[8];
        #pragma unroll
        for (int j = 0; j < 4; j++) {
            float ah = ftanh(PHr[sj[j]][tid] + xh);
            vals[j] = ah * ah;
            float pc  = (j < 3) ? PCcr[sj[j]][tid] : PChr[sj[j]][tid];
            float xcu = (j < 3) ? xc : xh;
            float ac = ftanh(pc + xcu);
            vals[4 + j] = ac * ac;
        }
        #pragma unroll
        for (int jj = 0; jj < 8; jj++) {
            float v = vals[jj];
            #pragma unroll
            for (int m = 32; m; m >>= 1) v += __shfl_xor(v, m, 64);
            if (lane == 0) red[jj * 4 + wid] = v;
        }
        __syncthreads();
        if (tid < 8) {
            sc8[tid] = sqrtf(red[tid * 4] + red[tid * 4 + 1] + red[tid * 4 + 2] + red[tid * 4 + 3]);
        }
        __syncthreads();
        if (tid < 2) {
            float s[4] = { sc8[tid * 4], sc8[tid * 4 + 1], sc8[tid * 4 + 2], sc8[tid * 4 + 3] };
            softmax4(s);
            #pragma unroll
            for (int j = 0; j < 4; j++) wsm[tid * 4 + j] = s[j];
        }
        __syncthreads();

        // ---- hmix / cmix ----
        {
            float ha = 0.f, ca = 0.f;
            #pragma unroll
            for (int j = 0; j < 4; j++) {
                ha = fmaf(wsm[j],     Hr[sj[j]][tid], ha);
                ca = fmaf(wsm[4 + j], Cr[sj[j]][tid], ca);
            }
            hm[tid] = fmaxf(ha, 0.f);
            cm[tid] = fmaxf(ca, 0.f);
        }
        __syncthreads();

        // ---- g = xg + hmix @ rk ; gates; new state ----
        {
            float a0 = 0.f, a1 = 0.f, a2 = 0.f, a3 = 0.f;
            const uint4* rbase = (const uint4*)rkP + tid;
            #pragma unroll 2
            for (int kc = 0; kc < 32; kc++) {
                float4 h0 = *(const float4*)&hm[kc * 8];
                float4 h1 = *(const float4*)&hm[kc * 8 + 4];
                const uint4* rp = rbase + kc * 1024;
                uint4 w0 = rp[0];
                uint4 w1 = rp[256];
                uint4 w2 = rp[512];
                uint4 w3 = rp[768];
                a0 = dot8(w0, h0, h1, a0);
                a1 = dot8(w1, h0, h1, a1);
                a2 = dot8(w2, h0, h1, a2);
                a3 = dot8(w3, h0, h1, a3);
            }
            float gi = hsig(a0 + bf2f(xg0));
            float gf = hsig(a1 + bf2f(xg1));
            float gm = hsig(a2 + bf2f(xg2));
            float go = hsig(a3 + bf2f(xg3));
            float c = gf * cm[tid] + gi * gm;
            float h = go * ftanh(c);
            Hr[st][tid] = h;
            Cr[st][tid] = c;
            hs[rowx * Un + tid] = h;
        }
        __syncthreads();

        // ---- projection caches for the new state ----
        {
            float ph = 0.f, pcc = 0.f, pch = 0.f;
            const uint4* whb = (const uint4*)WhP + tid;
            const uint4* wcb = (const uint4*)WcP + tid;
            #pragma unroll 2
            for (int kc = 0; kc < 32; kc++) {
                float4 h0 = *(const float4*)&Hr[st][kc * 8];
                float4 h1 = *(const float4*)&Hr[st][kc * 8 + 4];
                float4 c0 = *(const float4*)&Cr[st][kc * 8];
                float4 c1 = *(const float4*)&Cr[st][kc * 8 + 4];
                uint4 wh = whb[kc * 256];
                uint4 wc = wcb[kc * 256];
                ph  = dot8(wh, h0, h1, ph);
                pch = dot8(wh, c0, c1, pch);
                pcc = dot8(wc, c0, c1, pcc);
            }
            PHr[st][tid]  = ph;
            PCcr[st][tid] = pcc;
            PChr[st][tid] = pch;
        }
        __syncthreads();
    }
}

// ---------------------------------------------------------------------------
// Phase 3: ha = relu(outs@A11)@a2 ; hb = relu(x@A12)@a2_2 ; out = tanh(ha*outs+hb)
// ---------------------------------------------------------------------------
__global__ __launch_bounds__(256)
void final_k(const float* __restrict__ x, const float* __restrict__ hsF, const float* __restrict__ hsB,
             const float* __restrict__ at1, const float* __restrict__ at2, const float* __restrict__ at22,
             float* __restrict__ out)
{
    __shared__ __align__(16) float orow[8][512];
    __shared__ __align__(16) float xrow[8][512];
    __shared__ float has[8], hbs[8];
    const int tid = threadIdx.x;
    const int m0 = blockIdx.x * 8;
    for (int e = tid; e < 8 * 512; e += 256) {
        int r = e >> 9, k = e & 511;
        int m = m0 + r, b = m >> 9, t = m & 511;
        float ov = (k < 256) ? hsF[((size_t)t * Bn + b) * Un + k]
                             : hsB[((size_t)t * Bn + b) * Un + (k - 256)];
        orow[r][k] = ov;
        xrow[r][k] = x[((size_t)b * Tn + t) * Fn + k];
    }
    __syncthreads();
    const int r = tid >> 5, us = tid & 31;
    float ya[8] = {}, yb[8] = {};
    const float* pa0 = at1 + us * 8;
    const float* pb0 = at1 + (size_t)512 * 256 + us * 8;
    for (int k = 0; k < 512; k++) {
        float a  = orow[r][k];
        float xv = xrow[r][k];
        const float* pa = pa0 + (size_t)k * 256;
        const float* pb = pb0 + (size_t)k * 256;
        float4 wa0 = *(const float4*)pa;
        float4 wa1 = *(const float4*)(pa + 4);
        float4 wb0 = *(const float4*)pb;
        float4 wb1 = *(const float4*)(pb + 4);
        ya[0] += a * wa0.x; ya[1] += a * wa0.y; ya[2] += a * wa0.z; ya[3] += a * wa0.w;
        ya[4] += a * wa1.x; ya[5] += a * wa1.y; ya[6] += a * wa1.z; ya[7] += a * wa1.w;
        yb[0] += xv * wb0.x; yb[1] += xv * wb0.y; yb[2] += xv * wb0.z; yb[3] += xv * wb0.w;
        yb[4] += xv * wb1.x; yb[5] += xv * wb1.y; yb[6] += xv * wb1.z; yb[7] += xv * wb1.w;
    }
    float4 a20  = *(const float4*)(at2 + us * 8);
    float4 a21  = *(const float4*)(at2 + us * 8 + 4);
    float4 a220 = *(const float4*)(at22 + us * 8);
    float4 a221 = *(const float4*)(at22 + us * 8 + 4);
    float pa_s = fmaxf(ya[0], 0.f) * a20.x + fmaxf(ya[1], 0.f) * a20.y
               + fmaxf(ya[2], 0.f) * a20.z + fmaxf(ya[3], 0.f) * a20.w
               + fmaxf(ya[4], 0.f) * a21.x + fmaxf(ya[5], 0.f) * a21.y
               + fmaxf(ya[6], 0.f) * a21.z + fmaxf(ya[7], 0.f) * a21.w;
    float pb_s = fmaxf(yb[0], 0.f) * a220.x + fmaxf(yb[1], 0.f) * a220.y
               + fmaxf(yb[2], 0.f) * a220.z + fmaxf(yb[3], 0.f) * a220.w
               + fmaxf(yb[4], 0.f) * a221.x + fmaxf(yb[5], 0.f) * a221.y
               + fmaxf(yb[6], 0.f) * a221.z + fmaxf(yb[7], 0.f) * a221.w;
    #pragma unroll
    for (int m = 16; m; m >>= 1) {
        pa_s += __shfl_xor(pa_s, m, 32);
        pb_s += __shfl_xor(pb_s, m, 32);
    }
    if (us == 0) { has[r] = pa_s; hbs[r] = pb_s; }
    __syncthreads();
    for (int e = tid; e < 8 * 512; e += 256) {
        int rr = e >> 9, k = e & 511;
        float v = ftanh(has[rr] * orow[rr][k] + hbs[rr]);
        out[(size_t)(m0 + rr) * 512 + k] = v;
    }
}

// ---------------------------------------------------------------------------
extern "C" void kernel_launch(void* const* d_in, const int* in_sizes, int n_in,
                              void* d_out, int out_size, void* d_ws, size_t ws_size,
                              hipStream_t stream)
{
    (void)in_sizes; (void)n_in; (void)out_size; (void)ws_size;
    const float* x    = (const float*)d_in[0];
    const float* wk   = (const float*)d_in[1];  // kernel (F, 4U)
    const float* rk   = (const float*)d_in[2];  // recurrent_kernel (U, 4U)
    const float* ath  = (const float*)d_in[3];  // attention_h (F+U, U)
    const float* atc  = (const float*)d_in[4];  // attention_c (F+U, U)
    const float* at1  = (const float*)d_in[5];  // attention1 (2U+F, U)
    const float* at2  = (const float*)d_in[7];  // attention2 (U, 1)
    const float* at22 = (const float*)d_in[8];  // attention2_2 (U, 1)
    float* out = (float*)d_out;

    char* p = (char*)d_ws;
    auto take = [&](size_t bytes) { char* q = p; p += (bytes + 255) & ~(size_t)255; return q; };
    __hip_bfloat16* xg  = (__hip_bfloat16*)take((size_t)Tn * Bn * Gn * 2);  // 134 MB
    __hip_bfloat16* xWh = (__hip_bfloat16*)take((size_t)Tn * Bn * Un * 2);  //  33 MB
    __hip_bfloat16* xWc = (__hip_bfloat16*)take((size_t)Tn * Bn * Un * 2);
    float* hsF = (float*)take((size_t)Tn * Bn * Un * 4);                    //  67 MB
    float* hsB = (float*)take((size_t)Tn * Bn * Un * 4);
    __hip_bfloat16* rkP = (__hip_bfloat16*)take((size_t)32 * 1024 * 8 * 2); // 512 KB
    __hip_bfloat16* WhP = (__hip_bfloat16*)take((size_t)32 * 256 * 8 * 2);  // 128 KB
    __hip_bfloat16* WcP = (__hip_bfloat16*)take((size_t)32 * 256 * 8 * 2);

    // Phase 0/1: weight packing + x-projections (time-parallel)
    pack_w<<<64, 256, 0, stream>>>(rk, ath, atc, rkP, WhP, WcP);
    gemm_x<<<dim3(Gn / 64, (Bn * Tn) / 64), 256, 0, stream>>>(x, wk, Gn, xg);
    gemm_x<<<dim3(Un / 64, (Bn * Tn) / 64), 256, 0, stream>>>(x, ath + (size_t)Un * Un, Un, xWh);
    gemm_x<<<dim3(Un / 64, (Bn * Tn) / 64), 256, 0, stream>>>(x, atc + (size_t)Un * Un, Un, xWc);

    // Phase 2: batch-parallel bidirectional scan (no grid sync)
    recurrence<<<dim3(256), dim3(256), 0, stream>>>(xg, xWh, xWc, rkP, WhP, WcP, hsF, hsB);

    // Phase 3: output attention + tanh
    final_k<<<dim3((Bn * Tn) / 8), 256, 0, stream>>>(x, hsF, hsB, at1, at2, at22, out);
}

// Round 3
// 7228.691 us; speedup vs baseline: 5.9093x; 1.3828x over previous
//
#include <hip/hip_runtime.h>
#include <hip/hip_bf16.h>
#include <cstddef>
#include <cstdint>

#define DEVINL __device__ __forceinline__

constexpr int Bn = 128;   // batch
constexpr int Tn = 512;   // time
constexpr int Fn = 512;   // features
constexpr int Un = 256;   // units
constexpr int Gn = 1024;  // 4*U
constexpr int RS = 5;     // ring slots

typedef _Float16 h2t __attribute__((ext_vector_type(2)));
typedef short bf16x8 __attribute__((ext_vector_type(8)));
typedef float f32x4 __attribute__((ext_vector_type(4)));

DEVINL float ftanh(float x) { float e = __expf(2.f * x); return 1.f - 2.f / (e + 1.f); }
DEVINL float hsig(float x)  { return fminf(fmaxf(fmaf(x, 0.2f, 0.5f), 0.f), 1.f); }

DEVINL void softmax4(float* s) {
    float mx = fmaxf(fmaxf(s[0], s[1]), fmaxf(s[2], s[3]));
    float e0 = __expf(s[0] - mx), e1 = __expf(s[1] - mx);
    float e2 = __expf(s[2] - mx), e3 = __expf(s[3] - mx);
    float inv = 1.f / (e0 + e1 + e2 + e3);
    s[0] = e0 * inv; s[1] = e1 * inv; s[2] = e2 * inv; s[3] = e3 * inv;
}

// dot of 2 fp16 pairs: w (packed f16x2 as uint) . h -> acc
DEVINL float d2(unsigned int w, unsigned int h, float acc) {
#if __has_builtin(__builtin_amdgcn_fdot2)
    return __builtin_amdgcn_fdot2(__builtin_bit_cast(h2t, w), __builtin_bit_cast(h2t, h), acc, false);
#else
    h2t a = __builtin_bit_cast(h2t, w), b = __builtin_bit_cast(h2t, h);
    acc = fmaf((float)a.x, (float)b.x, acc);
    acc = fmaf((float)a.y, (float)b.y, acc);
    return acc;
#endif
}
// 8 fp16 weights (uint4) . 8 fp16 h-values (uint4) -> acc
DEVINL float dot8h(uint4 w, uint4 h, float acc) {
    acc = d2(w.x, h.x, acc);
    acc = d2(w.y, h.y, acc);
    acc = d2(w.z, h.z, acc);
    acc = d2(w.w, h.w, acc);
    return acc;
}

DEVINL unsigned short f2bf(float f) {  // round-to-nearest-even bf16
    unsigned int u = __builtin_bit_cast(unsigned int, f);
    u += 0x7fffu + ((u >> 16) & 1u);
    return (unsigned short)(u >> 16);
}

// ---------------------------------------------------------------------------
// pack x (fp32) -> bf16, same layout (M=B*T rows, 512 cols)
// ---------------------------------------------------------------------------
__global__ __launch_bounds__(256)
void pack_x(const float* __restrict__ x, unsigned short* __restrict__ xbf)
{
    size_t i = ((size_t)blockIdx.x * 256 + threadIdx.x) * 4;
    float4 v = *(const float4*)(x + i);
    ushort4 o;
    o.x = f2bf(v.x); o.y = f2bf(v.y); o.z = f2bf(v.z); o.w = f2bf(v.w);
    *(ushort4*)(xbf + i) = o;
}

// ---------------------------------------------------------------------------
// pack W (K=512 rows x N cols, fp32) -> Wt (N rows x 512 cols, bf16)
// ---------------------------------------------------------------------------
__global__ __launch_bounds__(256)
void wt_pack(const float* __restrict__ W, unsigned short* __restrict__ Wt, int N)
{
    int total = N * 512;
    for (int e = blockIdx.x * 256 + threadIdx.x; e < total; e += gridDim.x * 256) {
        int n = e >> 9, k = e & 511;
        Wt[e] = f2bf(W[(size_t)k * N + n]);
    }
}

// ---------------------------------------------------------------------------
// pack recurrence weights -> fp16, k-interleaved: P[(kc*N + n)*8 + i] = W[kc*8+i][n]
// ---------------------------------------------------------------------------
__global__ __launch_bounds__(256)
void pack_w(const float* __restrict__ rk, const float* __restrict__ ath,
            const float* __restrict__ atc,
            _Float16* __restrict__ rkP, _Float16* __restrict__ WhP,
            _Float16* __restrict__ WcP)
{
    int idx = blockIdx.x * 256 + threadIdx.x;
    const int stride = gridDim.x * 256;
    for (int e = idx; e < 32 * 1024 * 8; e += stride) {
        int i = e & 7, n = (e >> 3) & 1023, kc = e >> 13;
        rkP[e] = (_Float16)rk[(size_t)(kc * 8 + i) * Gn + n];
    }
    for (int e = idx; e < 32 * 256 * 8; e += stride) {
        int i = e & 7, n = (e >> 3) & 255, kc = e >> 11;
        WhP[e] = (_Float16)ath[(size_t)(kc * 8 + i) * Un + n];
        WcP[e] = (_Float16)atc[(size_t)(kc * 8 + i) * Un + n];
    }
}

// ---------------------------------------------------------------------------
// Phase 1: MFMA bf16 GEMM. Abf: (65536 x 512) bf16 row-major. Wt: (N x 512) bf16
// (pre-transposed). out fp16 at [(t*B+b)*N + n], m = b*512+t.
// Block 256 thr = 4 waves; 64x64 tile; wave w -> 16-row strip, 4 n-tiles.
// ---------------------------------------------------------------------------
__global__ __launch_bounds__(256)
void gemm_mfma(const unsigned short* __restrict__ Abf, const unsigned short* __restrict__ Wt,
               int N, _Float16* __restrict__ out)
{
    __shared__ __align__(16) unsigned short As[64][40];  // [m][k], stride 80B (16B-mult)
    __shared__ __align__(16) unsigned short Bs[64][40];  // [n][k]
    const int tid = threadIdx.x;
    const int n0 = blockIdx.x * 64, m0 = blockIdx.y * 64;
    const int w = tid >> 6, lane = tid & 63;
    const int fr = lane & 15, quad = lane >> 4;
    const int srow = tid >> 2, sk = (tid & 3) * 8;

    f32x4 acc[4];
    #pragma unroll
    for (int i = 0; i < 4; i++) acc[i] = (f32x4){0.f, 0.f, 0.f, 0.f};

    const unsigned short* ap = Abf + (size_t)(m0 + srow) * 512 + sk;
    const unsigned short* bp = Wt + (size_t)(n0 + srow) * 512 + sk;

    for (int k0 = 0; k0 < 512; k0 += 32) {
        uint4 av = *(const uint4*)(ap + k0);
        uint4 bv = *(const uint4*)(bp + k0);
        __syncthreads();
        *(uint4*)&As[srow][sk] = av;
        *(uint4*)&Bs[srow][sk] = bv;
        __syncthreads();
        bf16x8 a = *(const bf16x8*)&As[w * 16 + fr][quad * 8];
        #pragma unroll
        for (int nt = 0; nt < 4; nt++) {
            bf16x8 b = *(const bf16x8*)&Bs[nt * 16 + fr][quad * 8];
            acc[nt] = __builtin_amdgcn_mfma_f32_16x16x32_bf16(a, b, acc[nt], 0, 0, 0);
        }
    }
    #pragma unroll
    for (int nt = 0; nt < 4; nt++) {
        int n = n0 + nt * 16 + fr;
        #pragma unroll
        for (int reg = 0; reg < 4; reg++) {
            int m = m0 + w * 16 + quad * 4 + reg;
            int b = m >> 9, t = m & 511;
            out[((size_t)t * Bn + b) * N + n] = (_Float16)acc[nt][reg];
        }
    }
}

// ---------------------------------------------------------------------------
// Phase 2: recurrence. 128 WGs x 512 threads; WG handles (dir, 2 batch rows).
// One weight fetch serves both rows (halves L2 traffic); fp16 fdot2 GEMV core.
// ---------------------------------------------------------------------------
__global__ __launch_bounds__(512)
void recurrence(const _Float16* __restrict__ xg,
                const _Float16* __restrict__ xWh,
                const _Float16* __restrict__ xWc,
                const _Float16* __restrict__ rkP,
                const _Float16* __restrict__ WhP,
                const _Float16* __restrict__ WcP,
                float* __restrict__ hsF, float* __restrict__ hsB)
{
    const int tid = threadIdx.x;
    const int d = blockIdx.x >> 6;          // direction
    const int b0 = (blockIdx.x & 63) * 2;   // batch row pair

    __shared__ float Hr[2][RS][Un], Cr[2][RS][Un];
    __shared__ float PHr[2][RS][Un], PCcr[2][RS][Un], PChr[2][RS][Un];
    __shared__ __align__(16) unsigned int hm_pk[2][128];  // hmix fp16x2
    __shared__ __align__(16) unsigned int Hpk[2][128], Cpk[2][128];
    __shared__ float gtmp[2][4][Un];
    __shared__ float red[2][8][4];
    __shared__ float wsm[2][8];

    for (int e = tid; e < 2 * RS * Un; e += 512) {
        ((float*)Hr)[e] = 0.f; ((float*)Cr)[e] = 0.f;
        ((float*)PHr)[e] = 0.f; ((float*)PCcr)[e] = 0.f; ((float*)PChr)[e] = 0.f;
    }
    __syncthreads();

    const int r = tid >> 8, u = tid & 255;
    const int lane = tid & 63, wv = tid >> 6;
    float* hs = d ? hsB : hsF;

    for (int t = 0; t < Tn; t++) {
        const int tt = d ? (Tn - 1 - t) : t;
        const int st = t % RS;
        int sj[4];
        #pragma unroll
        for (int j = 0; j < 4; j++) sj[j] = (t - 1 - j + 2 * RS) % RS;

        const size_t rowx = (size_t)tt * Bn + (b0 + r);

        // prefetch per-(r,u) step inputs
        float xh  = (float)xWh[rowx * Un + u];
        float xc  = (float)xWc[rowx * Un + u];
        float xg0 = (float)xg[rowx * Gn + u];
        float xg1 = (float)xg[rowx * Gn + Un + u];
        float xg2 = (float)xg[rowx * Gn + 2 * Un + u];
        float xg3 = (float)xg[rowx * Gn + 3 * Un + u];

        // ---- scores ----
        float vals[8];
        #pragma unroll
        for (int j = 0; j < 4; j++) {
            float ah = ftanh(PHr[r][sj[j]][u] + xh);
            vals[j] = ah * ah;
            float pc  = (j < 3) ? PCcr[r][sj[j]][u] : PChr[r][sj[j]][u];
            float ac = ftanh(pc + ((j < 3) ? xc : xh));
            vals[4 + j] = ac * ac;
        }
        #pragma unroll
        for (int jj = 0; jj < 8; jj++) {
            float v = vals[jj];
            #pragma unroll
            for (int m = 32; m; m >>= 1) v += __shfl_xor(v, m, 64);
            if (lane == 0) red[r][jj][wv & 3] = v;
        }
        __syncthreads();
        if (tid < 4) {
            int rr = tid >> 1, hf = tid & 1;
            float s[4];
            #pragma unroll
            for (int j = 0; j < 4; j++) {
                const float* q = red[rr][hf * 4 + j];
                s[j] = sqrtf(q[0] + q[1] + q[2] + q[3]);
            }
            softmax4(s);
            #pragma unroll
            for (int j = 0; j < 4; j++) wsm[rr][hf * 4 + j] = s[j];
        }
        __syncthreads();

        // ---- hmix / cmix ----
        float ha = 0.f, ca = 0.f;
        #pragma unroll
        for (int j = 0; j < 4; j++) {
            ha = fmaf(wsm[r][j],     Hr[r][sj[j]][u], ha);
            ca = fmaf(wsm[r][4 + j], Cr[r][sj[j]][u], ca);
        }
        float hmv = fmaxf(ha, 0.f);
        float cmv = fmaxf(ca, 0.f);  // held in register until gate epilogue
        {
            float ho = __shfl_xor(hmv, 1, 64);
            if (!(tid & 1)) {
                h2t pk; pk.x = (_Float16)hmv; pk.y = (_Float16)ho;
                hm_pk[r][u >> 1] = __builtin_bit_cast(unsigned int, pk);
            }
        }
        __syncthreads();

        // ---- gate GEMV: cols c1=tid, c2=tid+512, both rows share weight loads ----
        float a00 = 0.f, a01 = 0.f, a10 = 0.f, a11 = 0.f;
        {
            const _Float16* p1 = rkP + (size_t)tid * 8;
            const _Float16* p2 = rkP + (size_t)(tid + 512) * 8;
            #pragma unroll 4
            for (int kc = 0; kc < 32; kc++) {
                uint4 w1 = *(const uint4*)(p1 + (size_t)kc * 8192);
                uint4 w2 = *(const uint4*)(p2 + (size_t)kc * 8192);
                uint4 h0 = *(const uint4*)&hm_pk[0][kc * 4];
                uint4 h1 = *(const uint4*)&hm_pk[1][kc * 4];
                a00 = dot8h(w1, h0, a00); a01 = dot8h(w2, h0, a01);
                a10 = dot8h(w1, h1, a10); a11 = dot8h(w2, h1, a11);
            }
        }
        {
            int q1 = tid >> 8, u1 = tid & 255;
            gtmp[0][q1][u1] = a00;  gtmp[0][q1 + 2][u1] = a01;
            gtmp[1][q1][u1] = a10;  gtmp[1][q1 + 2][u1] = a11;
        }
        __syncthreads();

        // ---- gates epilogue (r,u) ----
        {
            float g0 = gtmp[r][0][u] + xg0;
            float g1 = gtmp[r][1][u] + xg1;
            float g2 = gtmp[r][2][u] + xg2;
            float g3 = gtmp[r][3][u] + xg3;
            float gi = hsig(g0), gf = hsig(g1), gm = hsig(g2), go = hsig(g3);
            float c = gf * cmv + gi * gm;
            float h = go * ftanh(c);
            Hr[r][st][u] = h;
            Cr[r][st][u] = c;
            hs[rowx * Un + u] = h;
            float hho = __shfl_xor(h, 1, 64);
            float cco = __shfl_xor(c, 1, 64);
            if (!(tid & 1)) {
                h2t pk1; pk1.x = (_Float16)h; pk1.y = (_Float16)hho;
                h2t pk2; pk2.x = (_Float16)c; pk2.y = (_Float16)cco;
                Hpk[r][u >> 1] = __builtin_bit_cast(unsigned int, pk1);
                Cpk[r][u >> 1] = __builtin_bit_cast(unsigned int, pk2);
            }
        }
        __syncthreads();

        // ---- projection caches for new state ----
        if (tid < 256) {
            const int c = tid;
            const _Float16* pw = WhP + (size_t)c * 8;
            float ph0 = 0.f, ph1 = 0.f, pc0 = 0.f, pc1 = 0.f;
            #pragma unroll 4
            for (int kc = 0; kc < 32; kc++) {
                uint4 wv4 = *(const uint4*)(pw + (size_t)kc * 2048);
                uint4 H0 = *(const uint4*)&Hpk[0][kc * 4];
                uint4 H1 = *(const uint4*)&Hpk[1][kc * 4];
                uint4 C0 = *(const uint4*)&Cpk[0][kc * 4];
                uint4 C1 = *(const uint4*)&Cpk[1][kc * 4];
                ph0 = dot8h(wv4, H0, ph0); ph1 = dot8h(wv4, H1, ph1);
                pc0 = dot8h(wv4, C0, pc0); pc1 = dot8h(wv4, C1, pc1);
            }
            PHr[0][st][c] = ph0; PHr[1][st][c] = ph1;
            PChr[0][st][c] = pc0; PChr[1][st][c] = pc1;
        } else {
            const int c = tid - 256;
            const _Float16* pw = WcP + (size_t)c * 8;
            float pc0 = 0.f, pc1 = 0.f;
            #pragma unroll 4
            for (int kc = 0; kc < 32; kc++) {
                uint4 wv4 = *(const uint4*)(pw + (size_t)kc * 2048);
                uint4 C0 = *(const uint4*)&Cpk[0][kc * 4];
                uint4 C1 = *(const uint4*)&Cpk[1][kc * 4];
                pc0 = dot8h(wv4, C0, pc0); pc1 = dot8h(wv4, C1, pc1);
            }
            PCcr[0][st][c] = pc0; PCcr[1][st][c] = pc1;
        }
        __syncthreads();
    }
}

// ---------------------------------------------------------------------------
// Phase 3: ha = relu(outs@A11)@a2 ; hb = relu(x@A12)@a2_2 ; out = tanh(ha*outs+hb)
// ---------------------------------------------------------------------------
__global__ __launch_bounds__(256)
void final_k(const float* __restrict__ x, const float* __restrict__ hsF, const float* __restrict__ hsB,
             const float* __restrict__ at1, const float* __restrict__ at2, const float* __restrict__ at22,
             float* __restrict__ out)
{
    __shared__ __align__(16) float orow[8][512];
    __shared__ __align__(16) float xrow[8][512];
    __shared__ float has[8], hbs[8];
    const int tid = threadIdx.x;
    const int m0 = blockIdx.x * 8;
    for (int e = tid; e < 8 * 512; e += 256) {
        int r = e >> 9, k = e & 511;
        int m = m0 + r, b = m >> 9, t = m & 511;
        float ov = (k < 256) ? hsF[((size_t)t * Bn + b) * Un + k]
                             : hsB[((size_t)t * Bn + b) * Un + (k - 256)];
        orow[r][k] = ov;
        xrow[r][k] = x[((size_t)b * Tn + t) * Fn + k];
    }
    __syncthreads();
    const int r = tid >> 5, us = tid & 31;
    float ya[8] = {}, yb[8] = {};
    const float* pa0 = at1 + us * 8;
    const float* pb0 = at1 + (size_t)512 * 256 + us * 8;
    for (int k = 0; k < 512; k++) {
        float a  = orow[r][k];
        float xv = xrow[r][k];
        const float* pa = pa0 + (size_t)k * 256;
        const float* pb = pb0 + (size_t)k * 256;
        float4 wa0 = *(const float4*)pa;
        float4 wa1 = *(const float4*)(pa + 4);
        float4 wb0 = *(const float4*)pb;
        float4 wb1 = *(const float4*)(pb + 4);
        ya[0] += a * wa0.x; ya[1] += a * wa0.y; ya[2] += a * wa0.z; ya[3] += a * wa0.w;
        ya[4] += a * wa1.x; ya[5] += a * wa1.y; ya[6] += a * wa1.z; ya[7] += a * wa1.w;
        yb[0] += xv * wb0.x; yb[1] += xv * wb0.y; yb[2] += xv * wb0.z; yb[3] += xv * wb0.w;
        yb[4] += xv * wb1.x; yb[5] += xv * wb1.y; yb[6] += xv * wb1.z; yb[7] += xv * wb1.w;
    }
    float4 a20  = *(const float4*)(at2 + us * 8);
    float4 a21  = *(const float4*)(at2 + us * 8 + 4);
    float4 a220 = *(const float4*)(at22 + us * 8);
    float4 a221 = *(const float4*)(at22 + us * 8 + 4);
    float pa_s = fmaxf(ya[0], 0.f) * a20.x + fmaxf(ya[1], 0.f) * a20.y
               + fmaxf(ya[2], 0.f) * a20.z + fmaxf(ya[3], 0.f) * a20.w
               + fmaxf(ya[4], 0.f) * a21.x + fmaxf(ya[5], 0.f) * a21.y
               + fmaxf(ya[6], 0.f) * a21.z + fmaxf(ya[7], 0.f) * a21.w;
    float pb_s = fmaxf(yb[0], 0.f) * a220.x + fmaxf(yb[1], 0.f) * a220.y
               + fmaxf(yb[2], 0.f) * a220.z + fmaxf(yb[3], 0.f) * a220.w
               + fmaxf(yb[4], 0.f) * a221.x + fmaxf(yb[5], 0.f) * a221.y
               + fmaxf(yb[6], 0.f) * a221.z + fmaxf(yb[7], 0.f) * a221.w;
    #pragma unroll
    for (int m = 16; m; m >>= 1) {
        pa_s += __shfl_xor(pa_s, m, 32);
        pb_s += __shfl_xor(pb_s, m, 32);
    }
    if (us == 0) { has[r] = pa_s; hbs[r] = pb_s; }
    __syncthreads();
    for (int e = tid; e < 8 * 512; e += 256) {
        int rr = e >> 9, k = e & 511;
        float v = ftanh(has[rr] * orow[rr][k] + hbs[rr]);
        out[(size_t)(m0 + rr) * 512 + k] = v;
    }
}

// ---------------------------------------------------------------------------
extern "C" void kernel_launch(void* const* d_in, const int* in_sizes, int n_in,
                              void* d_out, int out_size, void* d_ws, size_t ws_size,
                              hipStream_t stream)
{
    (void)in_sizes; (void)n_in; (void)out_size; (void)ws_size;
    const float* x    = (const float*)d_in[0];
    const float* wk   = (const float*)d_in[1];  // kernel (F, 4U)
    const float* rk   = (const float*)d_in[2];  // recurrent_kernel (U, 4U)
    const float* ath  = (const float*)d_in[3];  // attention_h (F+U, U)
    const float* atc  = (const float*)d_in[4];  // attention_c (F+U, U)
    const float* at1  = (const float*)d_in[5];  // attention1 (2U+F, U)
    const float* at2  = (const float*)d_in[7];  // attention2 (U, 1)
    const float* at22 = (const float*)d_in[8];  // attention2_2 (U, 1)
    float* out = (float*)d_out;

    char* p = (char*)d_ws;
    auto take = [&](size_t bytes) { char* q = p; p += (bytes + 255) & ~(size_t)255; return q; };
    _Float16* xg  = (_Float16*)take((size_t)Tn * Bn * Gn * 2);   // 134 MB
    _Float16* xWh = (_Float16*)take((size_t)Tn * Bn * Un * 2);   //  33 MB
    _Float16* xWc = (_Float16*)take((size_t)Tn * Bn * Un * 2);
    float* hsF = (float*)take((size_t)Tn * Bn * Un * 4);         //  64 MiB
    float* hsB = (float*)take((size_t)Tn * Bn * Un * 4);
    _Float16* rkP = (_Float16*)take((size_t)Un * Gn * 2);        // 512 KB
    _Float16* WhP = (_Float16*)take((size_t)Un * Un * 2);        // 128 KB
    _Float16* WcP = (_Float16*)take((size_t)Un * Un * 2);
    unsigned short* Wt1 = (unsigned short*)take((size_t)Gn * Fn * 2);  // 1 MB
    unsigned short* Wt2 = (unsigned short*)take((size_t)Un * Fn * 2);
    unsigned short* Wt3 = (unsigned short*)take((size_t)Un * Fn * 2);
    // xbf (64 MiB) aliases hsF: only needed before recurrence writes hsF.
    unsigned short* xbf = (unsigned short*)hsF;

    // Phase 0: packing
    pack_x<<<32768, 256, 0, stream>>>(x, xbf);
    wt_pack<<<2048, 256, 0, stream>>>(wk, Wt1, Gn);
    wt_pack<<<1024, 256, 0, stream>>>(ath + (size_t)Un * Un, Wt2, Un);
    wt_pack<<<1024, 256, 0, stream>>>(atc + (size_t)Un * Un, Wt3, Un);
    pack_w<<<64, 256, 0, stream>>>(rk, ath, atc, rkP, WhP, WcP);

    // Phase 1: MFMA x-projections
    gemm_mfma<<<dim3(Gn / 64, (Bn * Tn) / 64), 256, 0, stream>>>(xbf, Wt1, Gn, xg);
    gemm_mfma<<<dim3(Un / 64, (Bn * Tn) / 64), 256, 0, stream>>>(xbf, Wt2, Un, xWh);
    gemm_mfma<<<dim3(Un / 64, (Bn * Tn) / 64), 256, 0, stream>>>(xbf, Wt3, Un, xWc);

    // Phase 2: recurrence (2 rows per WG, 8 waves)
    recurrence<<<dim3(128), dim3(512), 0, stream>>>(xg, xWh, xWc, rkP, WhP, WcP, hsF, hsB);

    // Phase 3: output attention + tanh
    final_k<<<dim3((Bn * Tn) / 8), 256, 0, stream>>>(x, hsF, hsB, at1, at2, at22, out);
}